// Round 9
// baseline (128.893 us; speedup 1.0000x reference)
//
#include <hip/hip_runtime.h>

// DifferentiableProjectionLayer: 262144 independent rows of 64 assets,
// 20 iters of {box clip + simplex shift + 8 disjoint group projections}.
//
// Mapping: 8 lanes per row; lane c owns the 8 CONTIGUOUS assets [8c, 8c+8).
// Since group(j) = j%8, asset 8c+k belongs to group k — each lane holds
// exactly one asset of every group, local index == group id. So:
//   - global I/O is directly 2x float4 per thread (no LDS transpose at all)
//   - group sums = one VECTOR butterfly: gs[k] allreduced across the 8
//     row-lanes in 3 DPP stages (xor1, xor2 quad_perm, row_half_mirror for
//     the cross-quad stage — any lower<->upper quad pairing completes a
//     sum reduction). Pure VALU; no ds_swizzle, no LDS, no barriers.
//   - all 8 group projections computed per-lane from gs[0..7] (bounds in
//     SGPRs); convergence check is lane-local.
//
// WAVE-UNIFORM EARLY EXIT (non-expansive fixed-point map): once an
// iteration's |shift| and all |d_g| < 1e-6, the remaining iterations move
// w by < 4e-5, far below the 9.2e-4 accuracy threshold. On this data ~94%
// of waves exit after iteration 1.
//
// proj_kernel handles both the structural case (one-hot A, uniform box,
// verified wave-uniformly on device) and a faithful generic Dykstra
// fallback in the same w[8] register shape (~40 VGPR worst case).

#define NA 64
#define NG 8
#define TOL 1e-6f

template <int CTRL>
__device__ __forceinline__ float dpp_add(float v) {
    const int o = __builtin_amdgcn_update_dpp(0, __builtin_bit_cast(int, v),
                                              CTRL, 0xF, 0xF, true);
    return v + __builtin_bit_cast(float, o);
}

__device__ __forceinline__ float row8_allreduce(float v) {
    v = dpp_add<0xB1>(v);    // xor1: quad_perm [1,0,3,2]
    v = dpp_add<0x4E>(v);    // xor2: quad_perm [2,3,0,1]
    v = dpp_add<0x141>(v);   // cross-quad: row_half_mirror (i -> 7-i per 8)
    return v;
}

__global__ __launch_bounds__(256) void proj_kernel(
    const float* __restrict__ x,
    const float* __restrict__ box_lb,
    const float* __restrict__ box_ub,
    const float* __restrict__ group_A,
    const float* __restrict__ group_lb,
    const float* __restrict__ group_ub,
    const int*  __restrict__ num_iter,
    float* __restrict__ out,
    int nrows)
{
    const int t = blockIdx.x * blockDim.x + threadIdx.x;
    const int r = t >> 3;                 // row
    const int c = t & 7;                  // chunk: assets [8c, 8c+8)
    const int lane = threadIdx.x & 63;
    if (r >= nrows) return;

    const float* __restrict__ xr = x + (size_t)r * NA + c * 8;
    float* __restrict__ outr = out + (size_t)r * NA + c * 8;

    // ---- load: 2x float4, fully coalesced, no transpose needed ----
    float w[8];
    {
        const float4 v0 = *reinterpret_cast<const float4*>(xr);
        const float4 v1 = *reinterpret_cast<const float4*>(xr + 4);
        w[0] = v0.x; w[1] = v0.y; w[2] = v0.z; w[3] = v0.w;
        w[4] = v1.x; w[5] = v1.y; w[6] = v1.z; w[7] = v1.w;
    }

    // ---- structural check (wave-uniform result) ----
    const float lb0 = box_lb[0], ub0 = box_ub[0];
    bool ok = (box_lb[lane] == lb0) && (box_ub[lane] == ub0) && (lb0 <= ub0);
#pragma unroll
    for (int g = 0; g < NG; ++g) {
        const float expect = ((lane & 7) == g) ? 1.0f : 0.0f;
        ok = ok && (group_A[g * NA + lane] == expect);
    }
    const bool fast = __all(ok);

    // group bounds -> SGPRs (wave-uniform loads)
    float glb_s[NG], gub_s[NG];
#pragma unroll
    for (int g = 0; g < NG; ++g) { glb_s[g] = group_lb[g]; gub_s[g] = group_ub[g]; }

    const int iters = *num_iter;
    float shift = 0.0f;

    if (fast) {
        // ============== FAST PATH (structural data) ==============
        // ns = 8 (+1e-9 vanishes in f32) => inv = 0.125f exact.
        const float inv8 = 1.0f / (8.0f + 1e-9f);

        for (int it = 0; it < iters; ++it) {
            // box clip; w[k] is this lane's asset of group k
#pragma unroll
            for (int k = 0; k < 8; ++k)
                w[k] = __builtin_amdgcn_fmed3f(w[k], lb0, ub0);

            // vector butterfly: gs[k] = sum of group k over the 8 row-lanes
            float gs[NG];
#pragma unroll
            for (int k = 0; k < 8; ++k) gs[k] = w[k];
#pragma unroll
            for (int k = 0; k < 8; ++k) gs[k] = dpp_add<0xB1>(gs[k]);
#pragma unroll
            for (int k = 0; k < 8; ++k) gs[k] = dpp_add<0x4E>(gs[k]);
#pragma unroll
            for (int k = 0; k < 8; ++k) gs[k] = dpp_add<0x141>(gs[k]);

            const float S = ((gs[0] + gs[1]) + (gs[2] + gs[3]))
                          + ((gs[4] + gs[5]) + (gs[6] + gs[7]));
            const float sh = fmaf(S, 1.0f / NA, -1.0f / NA);

            // all 8 group projections per-lane (bounds are SGPRs)
            float u[NG], dmax = 0.0f;
#pragma unroll
            for (int g = 0; g < NG; ++g) {
                const float Aw  = fmaf(-8.0f, sh, gs[g]);
                const float e1  = fmaxf(Aw - gub_s[g], 0.0f);
                const float Aw2 = Aw - e1;                    // e1*(8*inv8)==e1
                const float e2  = fminf(Aw2 - glb_s[g], 0.0f);
                const float d   = (e1 + e2) * inv8;
                u[g] = sh + d;
                dmax = fmaxf(dmax, __builtin_fabsf(d));
            }
#pragma unroll
            for (int k = 0; k < 8; ++k) w[k] -= u[k];

            if (__all(__builtin_fabsf(sh) < TOL && dmax < TOL))
                break;
        }
        // final box_simplex
#pragma unroll
        for (int k = 0; k < 8; ++k)
            w[k] = __builtin_amdgcn_fmed3f(w[k], lb0, ub0);
        const float s01 = w[0] + w[1], s23 = w[2] + w[3];
        const float s45 = w[4] + w[5], s67 = w[6] + w[7];
        const float S = row8_allreduce((s01 + s23) + (s45 + s67));
        shift = fmaf(S, 1.0f / NA, -1.0f / NA);
    } else {
        // ============== GENERIC PATH (faithful Dykstra) ==============
        float lbv[8], ubv[8];
        {
            const float4 a0 = *reinterpret_cast<const float4*>(box_lb + c * 8);
            const float4 a1 = *reinterpret_cast<const float4*>(box_lb + c * 8 + 4);
            const float4 b0 = *reinterpret_cast<const float4*>(box_ub + c * 8);
            const float4 b1 = *reinterpret_cast<const float4*>(box_ub + c * 8 + 4);
            lbv[0]=a0.x; lbv[1]=a0.y; lbv[2]=a0.z; lbv[3]=a0.w;
            lbv[4]=a1.x; lbv[5]=a1.y; lbv[6]=a1.z; lbv[7]=a1.w;
            ubv[0]=b0.x; ubv[1]=b0.y; ubv[2]=b0.z; ubv[3]=b0.w;
            ubv[4]=b1.x; ubv[5]=b1.y; ubv[6]=b1.z; ubv[7]=b1.w;
        }
        for (int it = 0; it < iters; ++it) {
            float S = 0.0f;
#pragma unroll
            for (int k = 0; k < 8; ++k) {
                w[k] = fminf(fmaxf(w[k], lbv[k]), ubv[k]);
                S += w[k];
            }
            S = row8_allreduce(S);
            const float sh = (S - 1.0f) * (1.0f / NA);
#pragma unroll
            for (int k = 0; k < 8; ++k) w[k] -= sh;

            for (int g = 0; g < NG; ++g) {        // sequential groups
                float a[8];
                {
                    const float4 q0 = *reinterpret_cast<const float4*>(group_A + g * NA + c * 8);
                    const float4 q1 = *reinterpret_cast<const float4*>(group_A + g * NA + c * 8 + 4);
                    a[0]=q0.x; a[1]=q0.y; a[2]=q0.z; a[3]=q0.w;
                    a[4]=q1.x; a[5]=q1.y; a[6]=q1.z; a[7]=q1.w;
                }
                float ns = 0.0f, Aw = 0.0f;
#pragma unroll
                for (int k = 0; k < 8; ++k) {
                    ns = fmaf(a[k], a[k], ns);
                    Aw = fmaf(a[k], w[k], Aw);
                }
                ns = row8_allreduce(ns);
                Aw = row8_allreduce(Aw);
                const float invg = 1.0f / (ns + 1e-9f);
                const float gub = gub_s[g], glb = glb_s[g];
                const float d1 = (Aw > gub) ? (Aw - gub) * invg : 0.0f;
#pragma unroll
                for (int k = 0; k < 8; ++k) w[k] = fmaf(-d1, a[k], w[k]);
                float Aw2 = 0.0f;
#pragma unroll
                for (int k = 0; k < 8; ++k) Aw2 = fmaf(a[k], w[k], Aw2);
                Aw2 = row8_allreduce(Aw2);
                const float d2 = (Aw2 < glb) ? (Aw2 - glb) * invg : 0.0f;
#pragma unroll
                for (int k = 0; k < 8; ++k) w[k] = fmaf(-d2, a[k], w[k]);
            }
        }
        float S = 0.0f;
#pragma unroll
        for (int k = 0; k < 8; ++k) {
            w[k] = fminf(fmaxf(w[k], lbv[k]), ubv[k]);
            S += w[k];
        }
        S = row8_allreduce(S);
        shift = (S - 1.0f) * (1.0f / NA);
    }

    // ---- store: 2x float4, coalesced ----
    {
        float4 v0, v1;
        v0.x = w[0] - shift; v0.y = w[1] - shift;
        v0.z = w[2] - shift; v0.w = w[3] - shift;
        v1.x = w[4] - shift; v1.y = w[5] - shift;
        v1.z = w[6] - shift; v1.w = w[7] - shift;
        *reinterpret_cast<float4*>(outr) = v0;
        *reinterpret_cast<float4*>(outr + 4) = v1;
    }
}

extern "C" void kernel_launch(void* const* d_in, const int* in_sizes, int n_in,
                              void* d_out, int out_size, void* d_ws, size_t ws_size,
                              hipStream_t stream) {
    const float* x        = (const float*)d_in[0];
    const float* box_lb   = (const float*)d_in[1];
    const float* box_ub   = (const float*)d_in[2];
    const float* group_A  = (const float*)d_in[3];
    const float* group_lb = (const float*)d_in[4];
    const float* group_ub = (const float*)d_in[5];
    const int*   num_iter = (const int*)d_in[6];
    float* out = (float*)d_out;

    const int nrows = in_sizes[0] / NA;          // 262144
    const int total = nrows * 8;                 // 8 lanes per row
    const int block = 256;
    const int grid = (total + block - 1) / block;

    proj_kernel<<<grid, block, 0, stream>>>(x, box_lb, box_ub, group_A,
                                            group_lb, group_ub, num_iter,
                                            out, nrows);
}